// Round 7
// baseline (67.292 us; speedup 1.0000x reference)
//
#include <hip/hip_runtime.h>
#include <hip/hip_bf16.h>

#define B_   4
#define C_   640
#define H_   64
#define W_   64
#define NT   512        // 8 waves
#define WVS  8          // waves per block
#define PXB  32         // pixels (columns) per block = half row
#define CPW  80         // channels per wave: WVS*CPW == C_
#define FWP  36         // lds_fw row stride (ushorts), padded vs 32 to spread banks

__device__ __forceinline__ unsigned short f2bf(float f) {
    __hip_bfloat16 h = __float2bfloat16(f);
    return __builtin_bit_cast(unsigned short, h);
}
__device__ __forceinline__ float bf2f(unsigned short u) {
    return __bfloat162float(__builtin_bit_cast(__hip_bfloat16, u));
}

// Accumulate one Fwarp row (4 px in r) against ft4 into a[12] (3 col-offsets x 4 px).
// Interior column neighbors via shfl with adjacent quad; block-edge via LDS halo.
__device__ __forceinline__ void row_acc(const float4 ft4, const float4 r,
                                        const int quad, const float hl, const float hr,
                                        float* a) {
    const float pw = __shfl_up(r.w, 1, 64);     // lane l-1's elem 3 (prev quad, same sub)
    const float nx = __shfl_down(r.x, 1, 64);   // lane l+1's elem 0 (next quad, same sub)
    const float vL0 = (quad == 0) ? hl : pw;    // left  halo col
    const float vR3 = (quad == 7) ? hr : nx;    // right halo col
    a[0]  = fmaf(ft4.x, vL0, a[0]);             // q = col-1
    a[1]  = fmaf(ft4.y, r.x, a[1]);
    a[2]  = fmaf(ft4.z, r.y, a[2]);
    a[3]  = fmaf(ft4.w, r.z, a[3]);
    a[4]  = fmaf(ft4.x, r.x, a[4]);             // q = center
    a[5]  = fmaf(ft4.y, r.y, a[5]);
    a[6]  = fmaf(ft4.z, r.z, a[6]);
    a[7]  = fmaf(ft4.w, r.w, a[7]);
    a[8]  = fmaf(ft4.x, r.y, a[8]);             // q = col+1
    a[9]  = fmaf(ft4.y, r.z, a[9]);
    a[10] = fmaf(ft4.z, r.w, a[10]);
    a[11] = fmaf(ft4.w, vR3, a[11]);
}

// Weighted sum of one Fwarp row into fwv[4]; at = attn[4px][9], r3 = 3*row.
__device__ __forceinline__ void row_fw(const float4 r, const int quad,
                                       const float hl, const float hr,
                                       const float* at, const int r3, float* fwv) {
    const float pw = __shfl_up(r.w, 1, 64);
    const float nx = __shfl_down(r.x, 1, 64);
    const float vL0 = (quad == 0) ? hl : pw;
    const float vR3 = (quad == 7) ? hr : nx;
    fwv[0] += at[0*9+r3]*vL0 + at[0*9+r3+1]*r.x + at[0*9+r3+2]*r.y;
    fwv[1] += at[1*9+r3]*r.x + at[1*9+r3+1]*r.y + at[1*9+r3+2]*r.z;
    fwv[2] += at[2*9+r3]*r.y + at[2*9+r3+1]*r.z + at[2*9+r3+2]*r.w;
    fwv[3] += at[3*9+r3]*r.z + at[3*9+r3+1]*r.w + at[3*9+r3+2]*vR3;
}

__global__ __launch_bounds__(NT, 4) void nca_fused(
    const float* __restrict__ Ft,
    const float* __restrict__ Fwp,
    const float* __restrict__ mask,
    const float* __restrict__ cw,
    const float* __restrict__ cb,
    float* __restrict__ out)
{
    __shared__ float lds_cw[2 * C_];              // 5 KB
    __shared__ float lds_msk[3][34];              // 0.4 KB  mask cols (with halo)
    __shared__ float lds_halo[3][2][C_];          // 15 KB   Fwp boundary cols
    __shared__ float lds_sim[WVS][PXB][9];        // 9 KB    sim partials
    __shared__ float lds_attn[PXB][9];            // 1.1 KB
    __shared__ float lds_red[WVS][PXB];           // 1 KB
    __shared__ float lds_lamT[PXB];
    __shared__ float lds_lam[PXB];
    __shared__ __hip_bfloat16 lds_fw[C_][FWP];    // 45 KB   weighted Fwarp (bf16)
    // total ~78.7 KB -> 2 blocks/CU

    const int t    = threadIdx.x;
    const int l    = t & 63;
    const int g    = t >> 6;        // wave id 0..7
    const int quad = l & 7;         // pixel quad 0..7
    const int sub  = l >> 3;        // channel subgroup 0..7
    const int w0   = quad * 4;      // first pixel (within half-row)

    // Decode: XCD x owns rows [x*8, x*8+8) (both halves, all batches). Bijective.
    const int n    = blockIdx.x;
    const int xcd  = n & 7;
    const int i    = n >> 3;                 // 0..63
    const int h    = xcd * 8 + (i & 7);
    const int half = (i >> 3) & 1;
    const int b    = i >> 4;

    const int hm = (h > 0) ? (h - 1) : 0;
    const int hp = (h < H_ - 1) ? (h + 1) : (H_ - 1);
    const int colL = half * PXB;             // global col of px 0
    const size_t cs = (size_t)H_ * W_;
    const int c0 = g * CPW;

    // ---- stage conv weights, mask (with halo), Fwp boundary columns -------
    for (int idx = t; idx < 2 * C_; idx += NT) lds_cw[idx] = cw[idx];
    if (t < 3 * 34) {
        const int r = t / 34, cl = t % 34;
        int gcol = colL + cl - 1;
        gcol = gcol < 0 ? 0 : (gcol > W_ - 1 ? W_ - 1 : gcol);
        const int row = (r == 0) ? hm : ((r == 1) ? h : hp);
        lds_msk[r][cl] = mask[((size_t)b * H_ + row) * W_ + gcol];
    }
    {
        const int hcl = (colL > 0) ? colL - 1 : 0;                 // replicate clamp
        const int hcr = (colL + PXB < W_) ? colL + PXB : W_ - 1;
        for (int idx = t; idx < 6 * C_; idx += NT) {
            const int c = idx % C_;
            const int rs = idx / C_;         // 0..5
            const int r = rs >> 1, side = rs & 1;
            const int row = (r == 0) ? hm : ((r == 1) ? h : hp);
            const int gcol = side ? hcr : hcl;
            lds_halo[r][side][c] = Fwp[((size_t)(b * C_ + c) * H_ + row) * W_ + gcol];
        }
    }
    __syncthreads();

    const size_t base = (size_t)(b * C_ + c0) * H_;
    const size_t lo   = (size_t)sub * cs + colL + w0;
    const float* ftp = Ft  + (base + h ) * W_ + lo;
    const float* q0p = Fwp + (base + hm) * W_ + lo;
    const float* q1p = Fwp + (base + h ) * W_ + lo;
    const float* q2p = Fwp + (base + hp) * W_ + lo;

    // ---------------- Pass A: sim partials -----------------------------------
    float acc[36];
    #pragma unroll
    for (int q = 0; q < 36; ++q) acc[q] = 0.f;
    float lamT4[4] = {0.f, 0.f, 0.f, 0.f};

    #pragma unroll 2
    for (int k = 0; k < CPW; k += 8) {
        const size_t off = (size_t)k * cs;
        const float4 ft4 = *(const float4*)(ftp + off);
        const float4 r0  = *(const float4*)(q0p + off);
        const float4 r1  = *(const float4*)(q1p + off);
        const float4 r2  = *(const float4*)(q2p + off);
        const int c = c0 + k + sub;
        const float wk = lds_cw[C_ + c];
        row_acc(ft4, r0, quad, lds_halo[0][0][c], lds_halo[0][1][c], &acc[0]);
        row_acc(ft4, r1, quad, lds_halo[1][0][c], lds_halo[1][1][c], &acc[12]);
        row_acc(ft4, r2, quad, lds_halo[2][0][c], lds_halo[2][1][c], &acc[24]);
        lamT4[0] = fmaf(wk, ft4.x, lamT4[0]);
        lamT4[1] = fmaf(wk, ft4.y, lamT4[1]);
        lamT4[2] = fmaf(wk, ft4.z, lamT4[2]);
        lamT4[3] = fmaf(wk, ft4.w, lamT4[3]);
    }

    // reduce the 8 channel-subgroups (xor over lane bits 3,4,5)
    #pragma unroll
    for (int q = 0; q < 36; ++q) {
        acc[q] += __shfl_xor(acc[q], 8, 64);
        acc[q] += __shfl_xor(acc[q], 16, 64);
        acc[q] += __shfl_xor(acc[q], 32, 64);
    }
    #pragma unroll
    for (int px = 0; px < 4; ++px) {
        lamT4[px] += __shfl_xor(lamT4[px], 8, 64);
        lamT4[px] += __shfl_xor(lamT4[px], 16, 64);
        lamT4[px] += __shfl_xor(lamT4[px], 32, 64);
    }

    // acc layout: [row r][colofs cc][px] at index (3r+cc... ) = [3r+cc]*? ->
    // acc[(r*3+cc)*4 + px] where within row_acc a[cc*4+px]. q index = r*3+cc.
    if (sub < 4) {                           // lane (quad, sub) writes px=sub
        const int px = sub;
        #pragma unroll
        for (int r = 0; r < 3; ++r)
            #pragma unroll
            for (int cc = 0; cc < 3; ++cc)
                lds_sim[g][w0 + px][r * 3 + cc] = acc[(r * 3 + cc) * 4 + px];
        lds_red[g][w0 + px] = lamT4[px];
    }
    __syncthreads();

    // ---------------- reduce across waves + mask -----------------------------
    if (t < PXB * 9) {
        const int ww = t / 9, q = t % 9;
        float s = 0.f;
        #pragma unroll
        for (int gg = 0; gg < WVS; ++gg) s += lds_sim[gg][ww][q];
        s *= 0.03952847075210474f;           // 1/sqrt(640)
        const int r = q / 3, j = q % 3;
        if (lds_msk[r][ww + j] == 1.0f) s = -1e9f;
        lds_attn[ww][q] = s;
    }
    __syncthreads();

    // ---------------- softmax per pixel + lamT reduce ------------------------
    if (t < PXB) {
        float v[9];
        float mx = -3e38f;
        bool valid = false;
        #pragma unroll
        for (int q = 0; q < 9; ++q) {
            v[q] = lds_attn[t][q];
            if (v[q] > -5e8f) valid = true;
            mx = fmaxf(mx, v[q]);
        }
        float lt = 0.f;
        #pragma unroll
        for (int gg = 0; gg < WVS; ++gg) lt += lds_red[gg][t];
        lds_lamT[t] = lt;
        if (!valid) {
            #pragma unroll
            for (int q = 0; q < 9; ++q) lds_attn[t][q] = 0.f;
        } else {
            float e[9], sum = 0.f;
            #pragma unroll
            for (int q = 0; q < 9; ++q) { e[q] = expf(v[q] - mx); sum += e[q]; }
            const float inv = 1.f / sum;
            #pragma unroll
            for (int q = 0; q < 9; ++q) lds_attn[t][q] = e[q] * inv;
        }
    }
    __syncthreads();

    // ---------------- Pass B: Fw (streams L2-warm) ---------------------------
    float at[36];                            // attn[px][q]
    #pragma unroll
    for (int px = 0; px < 4; ++px)
        #pragma unroll
        for (int q = 0; q < 9; ++q) at[px * 9 + q] = lds_attn[w0 + px][q];

    float lamF4[4] = {0.f, 0.f, 0.f, 0.f};
    #pragma unroll 2
    for (int k = 0; k < CPW; k += 8) {
        const size_t off = (size_t)k * cs;
        const float4 r0 = *(const float4*)(q0p + off);
        const float4 r1 = *(const float4*)(q1p + off);
        const float4 r2 = *(const float4*)(q2p + off);
        const int c = c0 + k + sub;
        float fwv[4] = {0.f, 0.f, 0.f, 0.f};
        row_fw(r0, quad, lds_halo[0][0][c], lds_halo[0][1][c], at, 0, fwv);
        row_fw(r1, quad, lds_halo[1][0][c], lds_halo[1][1][c], at, 3, fwv);
        row_fw(r2, quad, lds_halo[2][0][c], lds_halo[2][1][c], at, 6, fwv);
        ushort4 us;
        us.x = f2bf(fwv[0]); us.y = f2bf(fwv[1]);
        us.z = f2bf(fwv[2]); us.w = f2bf(fwv[3]);
        *(ushort4*)(&lds_fw[c][w0]) = us;
        const float wk = lds_cw[c];
        lamF4[0] = fmaf(wk, fwv[0], lamF4[0]);
        lamF4[1] = fmaf(wk, fwv[1], lamF4[1]);
        lamF4[2] = fmaf(wk, fwv[2], lamF4[2]);
        lamF4[3] = fmaf(wk, fwv[3], lamF4[3]);
    }
    #pragma unroll
    for (int px = 0; px < 4; ++px) {
        lamF4[px] += __shfl_xor(lamF4[px], 8, 64);
        lamF4[px] += __shfl_xor(lamF4[px], 16, 64);
        lamF4[px] += __shfl_xor(lamF4[px], 32, 64);
    }
    if (sub < 4) lds_red[g][w0 + sub] = lamF4[sub];
    __syncthreads();

    // ---------------- lambda = sigmoid(dot + bias) ---------------------------
    if (t < PXB) {
        float s = lds_lamT[t];
        #pragma unroll
        for (int gg = 0; gg < WVS; ++gg) s += lds_red[gg][t];
        s += cb[0];
        lds_lam[t] = 1.f / (1.f + expf(-s));
    }
    __syncthreads();

    // ---------------- Pass C: blend + store ----------------------------------
    float lam4[4], oml4[4];
    #pragma unroll
    for (int px = 0; px < 4; ++px) {
        lam4[px] = lds_lam[w0 + px];
        oml4[px] = 1.f - lam4[px];
    }
    float* outp = out + (base + h) * W_ + lo;
    #pragma unroll 2
    for (int k = 0; k < CPW; k += 8) {
        const size_t off = (size_t)k * cs;
        const float4 ft4 = *(const float4*)(ftp + off);
        const ushort4 us = *(const ushort4*)(&lds_fw[c0 + k + sub][w0]);
        float4 o;
        o.x = lam4[0] * ft4.x + oml4[0] * bf2f(us.x);
        o.y = lam4[1] * ft4.y + oml4[1] * bf2f(us.y);
        o.z = lam4[2] * ft4.z + oml4[2] * bf2f(us.z);
        o.w = lam4[3] * ft4.w + oml4[3] * bf2f(us.w);
        *(float4*)(outp + off) = o;
    }
}

extern "C" void kernel_launch(void* const* d_in, const int* in_sizes, int n_in,
                              void* d_out, int out_size, void* d_ws, size_t ws_size,
                              hipStream_t stream) {
    const float* Ft   = (const float*)d_in[0];
    const float* Fwp  = (const float*)d_in[1];
    const float* mask = (const float*)d_in[2];
    const float* cw   = (const float*)d_in[3];
    const float* cb   = (const float*)d_in[4];
    float* out = (float*)d_out;

    dim3 grid(B_ * H_ * 2);    // 512 blocks = 2 blocks/CU
    dim3 block(NT);
    nca_fused<<<grid, block, 0, stream>>>(Ft, Fwp, mask, cw, cb, out);
}